// Round 2
// baseline (232.929 us; speedup 1.0000x reference)
//
#include <hip/hip_runtime.h>
#include <hip/hip_bf16.h>

#define TPB 256

// ws layout (fp32 view):
//   ws[0]          mode flag: 1.0f = data is bf16, 0.0f = data is float32
//   W = ws+16:
//   W[0   ..255]   WA[k*8+j] = w1[j][k]      (u*m weights, transposed)
//   W[256 ..511]   WB[k*8+j] = w1[j][32+k]   (u weights)
//   W[512 ..767]   WC[k*8+j] = w1[j][64+k]   (m weights)
//   W[768 ..775]   B1[j]
//   W[776 ..783]   W2[j]
//   W[784]         B2

__device__ __forceinline__ float blo(unsigned int v) { return __uint_as_float(v << 16); }
__device__ __forceinline__ float bhi(unsigned int v) { return __uint_as_float(v & 0xffff0000u); }

__device__ __forceinline__ float readf(const void* p, int idx, int mode) {
    if (mode) return __uint_as_float(((unsigned int)((const unsigned short*)p)[idx]) << 16);
    return ((const float*)p)[idx];
}

__global__ void prep_kernel(const unsigned int* __restrict__ memb_words,
                            const void* __restrict__ w1,
                            const void* __restrict__ b1,
                            const void* __restrict__ w2,
                            const void* __restrict__ b2,
                            float* __restrict__ ws) {
    __shared__ float red[128];
    __shared__ int mode_sh;
    int t = threadIdx.x;
    // --- dtype detection: interpret first 128 words of movie_emb as bf16 pairs.
    // bf16 data: low half of each word is a real embedding value, |v| << 1.
    // fp32 data: low half is mantissa bits -> random exponent -> huge/NaN values.
    if (t < 128) {
        float a = fabsf(blo(memb_words[t]));
        if (!(a == a)) a = 1e30f;   // NaN -> large
        red[t] = a;
    }
    __syncthreads();
    if (t == 0) {
        float mx = 0.0f;
        for (int q = 0; q < 128; ++q) mx = fmaxf(mx, red[q]);
        int bf16_mode = (mx < 1.0f) ? 1 : 0;
        mode_sh = bf16_mode;
        ws[0] = (float)bf16_mode;
    }
    __syncthreads();
    int mode = mode_sh;
    float* W = ws + 16;
    for (int i = t; i < 768; i += TPB) {
        int grp = i >> 8;        // 0:WA(u*m) 1:WB(u) 2:WC(m)
        int r   = i & 255;
        int k   = r >> 3;
        int j   = r & 7;
        W[i] = readf(w1, j * 96 + grp * 32 + k, mode);
    }
    if (t < 8) W[768 + t] = readf(b1, t, mode);
    if (t < 8) W[776 + t] = readf(w2, t, mode);
    if (t == 0) W[784]    = readf(b2, 0, mode);
}

__global__ __launch_bounds__(TPB) void mf_kernel(
    const int* __restrict__ users, const int* __restrict__ movies,
    const void* __restrict__ uembv, const void* __restrict__ membv,
    const float* __restrict__ ws, void* __restrict__ outv, int n) {
    int i = blockIdx.x * TPB + threadIdx.x;
    if (i >= n) return;

    int mode = (int)ws[0];   // wave-uniform branch selector
    const float* W = ws + 16;

    int ui = users[i];
    int mi = movies[i];

    float u[32], m[32];
    if (mode) {
        // bf16 rows: 64 B each = 4 x uint4
        const uint4* up = (const uint4*)uembv + ((size_t)ui << 2);
        const uint4* mp = (const uint4*)membv + ((size_t)mi << 2);
        uint4 a0 = up[0], a1 = up[1], a2 = up[2], a3 = up[3];
        uint4 c0 = mp[0], c1 = mp[1], c2 = mp[2], c3 = mp[3];
        unsigned int wa[16] = {a0.x, a0.y, a0.z, a0.w, a1.x, a1.y, a1.z, a1.w,
                               a2.x, a2.y, a2.z, a2.w, a3.x, a3.y, a3.z, a3.w};
        unsigned int wc[16] = {c0.x, c0.y, c0.z, c0.w, c1.x, c1.y, c1.z, c1.w,
                               c2.x, c2.y, c2.z, c2.w, c3.x, c3.y, c3.z, c3.w};
#pragma unroll
        for (int d = 0; d < 16; ++d) {
            u[2 * d] = blo(wa[d]); u[2 * d + 1] = bhi(wa[d]);
            m[2 * d] = blo(wc[d]); m[2 * d + 1] = bhi(wc[d]);
        }
    } else {
        // fp32 rows: 128 B each = 8 x float4
        const float4* up = (const float4*)uembv + ((size_t)ui << 3);
        const float4* mp = (const float4*)membv + ((size_t)mi << 3);
#pragma unroll
        for (int q = 0; q < 8; ++q) {
            float4 a = up[q], c = mp[q];
            u[4 * q] = a.x; u[4 * q + 1] = a.y; u[4 * q + 2] = a.z; u[4 * q + 3] = a.w;
            m[4 * q] = c.x; m[4 * q + 1] = c.y; m[4 * q + 2] = c.z; m[4 * q + 3] = c.w;
        }
    }

    float h[8];
#pragma unroll
    for (int j = 0; j < 8; ++j) h[j] = W[768 + j];

#pragma unroll
    for (int k = 0; k < 32; ++k) {
        float uk = u[k], mk = m[k];
        float p = uk * mk;
#pragma unroll
        for (int j = 0; j < 8; ++j) {
            h[j] = fmaf(p,  W[k * 8 + j],        h[j]);
            h[j] = fmaf(uk, W[256 + k * 8 + j],  h[j]);
            h[j] = fmaf(mk, W[512 + k * 8 + j],  h[j]);
        }
    }

    float z = W[784];
#pragma unroll
    for (int j = 0; j < 8; ++j) z = fmaf(fmaxf(h[j], 0.0f), W[776 + j], z);

    float r = 1.0f / (1.0f + __expf(-z));
    if (mode) ((__hip_bfloat16*)outv)[i] = __float2bfloat16(r);
    else      ((float*)outv)[i] = r;
}

extern "C" void kernel_launch(void* const* d_in, const int* in_sizes, int n_in,
                              void* d_out, int out_size, void* d_ws, size_t ws_size,
                              hipStream_t stream) {
    const int* users  = (const int*)d_in[0];
    const int* movies = (const int*)d_in[1];
    const void* uemb  = d_in[2];   // [1e6, 32]  bf16 or fp32 (runtime-detected)
    const void* memb  = d_in[3];   // [1e5, 32]
    const void* w1    = d_in[4];   // [8, 96]
    const void* b1    = d_in[5];   // [8]
    const void* w2    = d_in[6];   // [1, 8]
    const void* b2    = d_in[7];   // [1]
    float* ws = (float*)d_ws;

    int n = in_sizes[0];

    prep_kernel<<<1, TPB, 0, stream>>>((const unsigned int*)memb, w1, b1, w2, b2, ws);
    mf_kernel<<<(n + TPB - 1) / TPB, TPB, 0, stream>>>(users, movies, uemb, memb, ws, d_out, n);
}